// Round 3
// baseline (449.240 us; speedup 1.0000x reference)
//
#include <hip/hip_runtime.h>

typedef unsigned short u16;
typedef __bf16 bf16x8 __attribute__((ext_vector_type(8)));
typedef unsigned short ushort8 __attribute__((ext_vector_type(8)));
typedef float floatx4 __attribute__((ext_vector_type(4)));

#define S_LEN 2048
#define DMODEL 2048
#define NH 32
#define NKV 8
#define HD_ 64

__device__ __forceinline__ u16 f2bf(float f) {
  unsigned u = __builtin_bit_cast(unsigned, f);
  u += 0x7FFF + ((u >> 16) & 1);   // round-to-nearest-even
  return (u16)(u >> 16);
}
__device__ __forceinline__ float bf2f(u16 h) {
  unsigned u = ((unsigned)h) << 16;
  return __builtin_bit_cast(float, u);
}
__device__ __forceinline__ bf16x8 ld8(const u16* p) {
  return __builtin_bit_cast(bf16x8, *(const ushort8*)p);
}
__device__ __forceinline__ floatx4 mfma16(bf16x8 a, bf16x8 b, floatx4 c) {
  return __builtin_amdgcn_mfma_f32_16x16x32_bf16(a, b, c, 0, 0, 0);
}
__device__ __forceinline__ void gload_lds16(const u16* g, u16* l) {
  __builtin_amdgcn_global_load_lds((const __attribute__((address_space(1))) void*)g,
                                   (__attribute__((address_space(3))) void*)l, 16, 0, 0);
}

// ---------------- fp32 -> bf16 convert (vectorized) ----------------
__global__ void cvt_kernel(const float* __restrict__ in, u16* __restrict__ out, int n4) {
  int i = blockIdx.x * blockDim.x + threadIdx.x;
  if (i >= n4) return;
  float4 v = ((const float4*)in)[i];
  ((ushort4*)out)[i] = make_ushort4(f2bf(v.x), f2bf(v.y), f2bf(v.z), f2bf(v.w));
}

// ---------------- GEMM: C[M][N] = A[M][K] @ B[N][K]^T (bf16 in, fp32 acc) ----------------
// 128x128 tile, BK=32, 256 threads = 4 waves (2x2), each wave 64x64 = 4x4 MFMA tiles.
template <int OUT_BF16>
__global__ __launch_bounds__(256) void gemm_bt(const u16* __restrict__ A, const u16* __restrict__ B,
                                               void* __restrict__ C, int M, int N, int K) {
  __shared__ __align__(16) u16 As[128 * 32];
  __shared__ __align__(16) u16 Bs[128 * 32];
  const int tid = threadIdx.x;
  const int wave = tid >> 6, lane = tid & 63;
  const int quad = lane >> 4, l16 = lane & 15;
  const int bm = blockIdx.y * 128, bn = blockIdx.x * 128;
  const int wr = (wave >> 1) * 64, wc = (wave & 1) * 64;
  floatx4 acc[4][4] = {};

  for (int k0 = 0; k0 < K; k0 += 32) {
    // stage A,B tiles: 8KB each = 8 chunks of 1KB; wave w stages chunks {w, w+4}
    for (int c = wave; c < 8; c += 4) {
      int e = c * 512 + lane * 8;          // element index in 128x32 tile
      int row = e >> 5, col = e & 31;
      gload_lds16(A + (size_t)(bm + row) * K + k0 + col, &As[c * 512]);
      gload_lds16(B + (size_t)(bn + row) * K + k0 + col, &Bs[c * 512]);
    }
    __syncthreads();   // vmcnt(0) drained here; LDS visible
    bf16x8 af[4], bfr[4];
#pragma unroll
    for (int i = 0; i < 4; i++) {
      af[i]  = ld8(&As[(wr + i * 16 + l16) * 32 + quad * 8]);
      bfr[i] = ld8(&Bs[(wc + i * 16 + l16) * 32 + quad * 8]);
    }
#pragma unroll
    for (int mi = 0; mi < 4; mi++)
#pragma unroll
      for (int ni = 0; ni < 4; ni++)
        acc[mi][ni] = mfma16(af[mi], bfr[ni], acc[mi][ni]);
    __syncthreads();   // protect LDS from next iteration's staging
  }

#pragma unroll
  for (int mi = 0; mi < 4; mi++)
#pragma unroll
    for (int ni = 0; ni < 4; ni++)
#pragma unroll
      for (int r = 0; r < 4; r++) {
        int row = bm + wr + mi * 16 + quad * 4 + r;   // C/D: row=(lane>>4)*4+reg
        int col = bn + wc + ni * 16 + l16;            //      col=lane&15
        float v = acc[mi][ni][r];
        if (OUT_BF16) ((u16*)C)[(size_t)row * N + col] = f2bf(v);
        else          ((float*)C)[(size_t)row * N + col] = v;
      }
}

// ---------------- RoPE in-place on bf16 (S, nheads, 64) ----------------
__global__ void rope_kernel(u16* __restrict__ qk, const float* __restrict__ fc, int h_bits) {
  int idx = blockIdx.x * blockDim.x + threadIdx.x;   // over S * nheads * 32 pairs
  int d = idx & 31;
  int t = idx >> 5;
  int hh = t & ((1 << h_bits) - 1);
  int s = t >> h_bits;
  float c  = fc[s * 64 + d * 2];
  float sn = fc[s * 64 + d * 2 + 1];
  size_t base = (((size_t)s << h_bits) + (size_t)hh) * 64 + d * 2;
  float x0 = bf2f(qk[base]), x1 = bf2f(qk[base + 1]);
  qk[base]     = f2bf(x0 * c - x1 * sn);
  qk[base + 1] = f2bf(x0 * sn + x1 * c);
}

// ---------------- V transpose: (S, KV, HD) -> (KV, HD, S) ----------------
__global__ void transpose_v(const u16* __restrict__ v, u16* __restrict__ vT) {
  int idx = blockIdx.x * blockDim.x + threadIdx.x;   // over KV*HD*S
  int s = idx & (S_LEN - 1);
  int t = idx >> 11;
  int hd = t & 63, g = t >> 6;
  vT[idx] = v[((size_t)s * NKV + g) * HD_ + hd];
}

// ---------------- Flash attention (causal, GQA) ----------------
// block = (head h, 64 q rows); 4 waves x 16 q rows; 32-key tiles.
// O is written IN-PLACE over q: each block reads only its own q rows (at start)
// and writes the same region (at end) — no cross-block overlap.
__global__ __launch_bounds__(256) void attn_kernel(u16* __restrict__ q, const u16* __restrict__ k,
                                                   const u16* __restrict__ vT) {
  __shared__ __align__(16) u16 pS[4][16 * 32];   // per-wave P scratch (C-layout -> A-layout)
  const int h = blockIdx.x;
  const int qt = blockIdx.y;
  const int g = h >> 2;                          // kv head = h / R, R=4
  const int wave = threadIdx.x >> 6, lane = threadIdx.x & 63;
  const int quad = lane >> 4, l16 = lane & 15;
  const int qrow0 = qt * 64 + wave * 16;

  const u16* qbase = q + ((size_t)(qrow0 + l16) * NH + h) * HD_ + quad * 8;
  bf16x8 qf0 = ld8(qbase);          // A-frag: m=lane&15 (q row), k=quad*8+j (hd 0..31)
  bf16x8 qf1 = ld8(qbase + 32);     // hd 32..63

  floatx4 Ofrag[4] = {};            // O[16 q][64 hd] over 4 n-tiles, C-layout
  float m_run[4], l_run[4];
#pragma unroll
  for (int r = 0; r < 4; r++) { m_run[r] = -INFINITY; l_run[r] = 0.f; }

  const int ktiles = ((qrow0 + 15) >> 5) + 1;    // causal: keys <= max row in this wave
  u16* myP = &pS[wave][0];

  for (int kt = 0; kt < ktiles; kt++) {
    const int kbase = kt * 32;
    // ---- QK^T: S[16 q][32 keys] as two C-frags ----
    floatx4 sf0 = {}, sf1 = {};
    const u16* kb0 = k + ((size_t)(kbase + l16) * NKV + g) * HD_ + quad * 8;
    sf0 = mfma16(qf0, ld8(kb0), sf0);
    sf0 = mfma16(qf1, ld8(kb0 + 32), sf0);
    const u16* kb1 = kb0 + (size_t)16 * NKV * HD_;
    sf1 = mfma16(qf0, ld8(kb1), sf1);
    sf1 = mfma16(qf1, ld8(kb1 + 32), sf1);

    // ---- online softmax update (per q row; row = quad*4+r, cols = lane&15 within n-tile) ----
#pragma unroll
    for (int r = 0; r < 4; r++) {
      const int rowg = qrow0 + quad * 4 + r;
      float s0 = sf0[r] * 0.125f;
      float s1 = sf1[r] * 0.125f;
      if (kbase + l16 > rowg)      s0 = -INFINITY;
      if (kbase + 16 + l16 > rowg) s1 = -INFINITY;
      float mt = fmaxf(s0, s1);
      mt = fmaxf(mt, __shfl_xor(mt, 1));
      mt = fmaxf(mt, __shfl_xor(mt, 2));
      mt = fmaxf(mt, __shfl_xor(mt, 4));
      mt = fmaxf(mt, __shfl_xor(mt, 8));
      float m_new = fmaxf(m_run[r], mt);
      float alpha = __expf(m_run[r] - m_new);   // first tile: exp(-inf)=0, safe
      float p0 = __expf(s0 - m_new);            // masked -> exp(-inf)=0
      float p1 = __expf(s1 - m_new);
      float rs = p0 + p1;
      rs += __shfl_xor(rs, 1);
      rs += __shfl_xor(rs, 2);
      rs += __shfl_xor(rs, 4);
      rs += __shfl_xor(rs, 8);
      l_run[r] = l_run[r] * alpha + rs;
      m_run[r] = m_new;
#pragma unroll
      for (int nt = 0; nt < 4; nt++) Ofrag[nt][r] *= alpha;
      myP[(quad * 4 + r) * 32 + l16]      = f2bf(p0);
      myP[(quad * 4 + r) * 32 + 16 + l16] = f2bf(p1);
    }
    asm volatile("s_waitcnt lgkmcnt(0)" ::: "memory");  // wave-local LDS write->read fence
    // ---- P (A-layout) @ V ----
    bf16x8 pf = ld8(&myP[l16 * 32 + quad * 8]);
#pragma unroll
    for (int nt = 0; nt < 4; nt++) {
      const u16* vb = vT + ((size_t)g * HD_ + nt * 16 + l16) * S_LEN + kbase + quad * 8;
      Ofrag[nt] = mfma16(pf, ld8(vb), Ofrag[nt]);
    }
  }

#pragma unroll
  for (int nt = 0; nt < 4; nt++)
#pragma unroll
    for (int r = 0; r < 4; r++) {
      int rowg = qrow0 + quad * 4 + r;
      float val = Ofrag[nt][r] / l_run[r];
      q[((size_t)rowg * NH + h) * HD_ + nt * 16 + l16] = f2bf(val);
    }
}

extern "C" void kernel_launch(void* const* d_in, const int* in_sizes, int n_in,
                              void* d_out, int out_size, void* d_ws, size_t ws_size,
                              hipStream_t stream) {
  const float* x  = (const float*)d_in[0];
  const float* fc = (const float*)d_in[1];
  const float* wq = (const float*)d_in[2];
  const float* wk = (const float*)d_in[3];
  const float* wv = (const float*)d_in[4];
  const float* wo = (const float*)d_in[5];
  float* out = (float*)d_out;

  // Workspace layout with lifetime reuse — 30 MB total:
  //   xb  [0,8MB)    x bf16                (live: cvt .. v-gemm)
  //   W1  [8,16MB)   wq bf16 -> wo bf16    (wq live until q-gemm; wo from then on)
  //   W2  [16,18MB)  wk bf16 -> v bf16     (wk live until k-gemm; v written by v-gemm)
  //   W3  [18,20MB)  wv bf16 -> vT bf16    (wv live until v-gemm; vT written by transpose)
  //   qb  [20,28MB)  q bf16 -> attn output (in-place)
  //   kb  [28,30MB)  k bf16
  char* ws = (char*)d_ws;
  const size_t MB = 1024 * 1024;
  u16* xb = (u16*)(ws);
  u16* W1 = (u16*)(ws + 8 * MB);
  u16* W2 = (u16*)(ws + 16 * MB);
  u16* W3 = (u16*)(ws + 18 * MB);
  u16* qb = (u16*)(ws + 20 * MB);
  u16* kb = (u16*)(ws + 28 * MB);
  (void)ws_size; (void)n_in; (void)in_sizes; (void)out_size;

  // 1) convert fp32 -> bf16
  cvt_kernel<<<4096, 256, 0, stream>>>(x,  xb, 1048576);
  cvt_kernel<<<4096, 256, 0, stream>>>(wq, W1, 1048576);
  cvt_kernel<<<1024, 256, 0, stream>>>(wk, W2, 262144);
  cvt_kernel<<<1024, 256, 0, stream>>>(wv, W3, 262144);

  // 2) Q projection, then recycle W1 for wo
  gemm_bt<1><<<dim3(16, 16), 256, 0, stream>>>(xb, W1, qb, S_LEN, DMODEL, DMODEL);
  cvt_kernel<<<4096, 256, 0, stream>>>(wo, W1, 1048576);

  // 3) K projection, then recycle W2 for v
  gemm_bt<1><<<dim3(4, 16),  256, 0, stream>>>(xb, W2, kb, S_LEN, 512, DMODEL);
  gemm_bt<1><<<dim3(4, 16),  256, 0, stream>>>(xb, W3, W2, S_LEN, 512, DMODEL);  // v -> W2

  // 4) RoPE (in place) + V transpose (W2 -> W3; wv dead)
  rope_kernel<<<8192, 256, 0, stream>>>(qb, fc, 5);   // 32 heads
  rope_kernel<<<2048, 256, 0, stream>>>(kb, fc, 3);   // 8 kv heads
  transpose_v<<<4096, 256, 0, stream>>>(W2, W3);

  // 5) causal GQA flash attention; output in-place into qb
  attn_kernel<<<dim3(NH, S_LEN / 64), 256, 0, stream>>>(qb, kb, W3);

  // 6) output projection (fp32 out)
  gemm_bt<0><<<dim3(16, 16), 256, 0, stream>>>(qb, W1, out, S_LEN, DMODEL, DMODEL);
}

// Round 4
// 408.253 us; speedup vs baseline: 1.1004x; 1.1004x over previous
//
#include <hip/hip_runtime.h>

typedef unsigned short u16;
typedef unsigned int u32;
typedef __bf16 bf16x8 __attribute__((ext_vector_type(8)));
typedef unsigned short ushort8 __attribute__((ext_vector_type(8)));
typedef float floatx4 __attribute__((ext_vector_type(4)));

#define S_LEN 2048
#define DMODEL 2048
#define NH 32
#define NKV 8
#define HD_ 64

__device__ __forceinline__ u16 f2bf(float f) {
  unsigned u = __builtin_bit_cast(unsigned, f);
  u += 0x7FFF + ((u >> 16) & 1);   // round-to-nearest-even
  return (u16)(u >> 16);
}
__device__ __forceinline__ float bf2f(u16 h) {
  unsigned u = ((unsigned)h) << 16;
  return __builtin_bit_cast(float, u);
}
__device__ __forceinline__ bf16x8 ld8(const u16* p) {
  return __builtin_bit_cast(bf16x8, *(const ushort8*)p);
}
__device__ __forceinline__ floatx4 mfma16(bf16x8 a, bf16x8 b, floatx4 c) {
  return __builtin_amdgcn_mfma_f32_16x16x32_bf16(a, b, c, 0, 0, 0);
}
__device__ __forceinline__ void gload_lds16(const u16* g, u16* l) {
  __builtin_amdgcn_global_load_lds((const __attribute__((address_space(1))) void*)g,
                                   (__attribute__((address_space(3))) void*)l, 16, 0, 0);
}

// ---------------- fp32 -> bf16 convert (vectorized) ----------------
__global__ void cvt_kernel(const float* __restrict__ in, u16* __restrict__ out, int n4) {
  int i = blockIdx.x * blockDim.x + threadIdx.x;
  if (i >= n4) return;
  float4 v = ((const float4*)in)[i];
  ((ushort4*)out)[i] = make_ushort4(f2bf(v.x), f2bf(v.y), f2bf(v.z), f2bf(v.w));
}

// ---------------- GEMM: C[M][N] = A[M][K] @ B[N][K]^T (bf16 in, fp32 acc) ----------------
// 128x128 tile, BK=32, 256 threads = 4 waves (2x2), each wave 64x64 = 4x4 MFMA tiles.
template <int OUT_BF16>
__global__ __launch_bounds__(256) void gemm_bt(const u16* __restrict__ A, const u16* __restrict__ B,
                                               void* __restrict__ C, int M, int N, int K) {
  __shared__ __align__(16) u16 As[128 * 32];
  __shared__ __align__(16) u16 Bs[128 * 32];
  const int tid = threadIdx.x;
  const int wave = tid >> 6, lane = tid & 63;
  const int quad = lane >> 4, l16 = lane & 15;
  const int bm = blockIdx.y * 128, bn = blockIdx.x * 128;
  const int wr = (wave >> 1) * 64, wc = (wave & 1) * 64;
  floatx4 acc[4][4] = {};

  for (int k0 = 0; k0 < K; k0 += 32) {
    for (int c = wave; c < 8; c += 4) {
      int e = c * 512 + lane * 8;          // element index in 128x32 tile
      int row = e >> 5, col = e & 31;
      gload_lds16(A + (size_t)(bm + row) * K + k0 + col, &As[c * 512]);
      gload_lds16(B + (size_t)(bn + row) * K + k0 + col, &Bs[c * 512]);
    }
    __syncthreads();
    bf16x8 af[4], bfr[4];
#pragma unroll
    for (int i = 0; i < 4; i++) {
      af[i]  = ld8(&As[(wr + i * 16 + l16) * 32 + quad * 8]);
      bfr[i] = ld8(&Bs[(wc + i * 16 + l16) * 32 + quad * 8]);
    }
#pragma unroll
    for (int mi = 0; mi < 4; mi++)
#pragma unroll
      for (int ni = 0; ni < 4; ni++)
        acc[mi][ni] = mfma16(af[mi], bfr[ni], acc[mi][ni]);
    __syncthreads();
  }

#pragma unroll
  for (int mi = 0; mi < 4; mi++)
#pragma unroll
    for (int ni = 0; ni < 4; ni++)
#pragma unroll
      for (int r = 0; r < 4; r++) {
        int row = bm + wr + mi * 16 + quad * 4 + r;
        int col = bn + wc + ni * 16 + l16;
        float v = acc[mi][ni][r];
        if (OUT_BF16) ((u16*)C)[(size_t)row * N + col] = f2bf(v);
        else          ((float*)C)[(size_t)row * N + col] = v;
      }
}

// ---------------- RoPE in-place on bf16, rows of `row_stride`, nheads = 1<<h_bits ----------------
__global__ void rope_kernel(u16* __restrict__ qk, const float* __restrict__ fc, int h_bits,
                            int row_stride, float scale) {
  int idx = blockIdx.x * blockDim.x + threadIdx.x;   // over S * nheads * 32 pairs
  int d = idx & 31;
  int t = idx >> 5;
  int hh = t & ((1 << h_bits) - 1);
  int s = t >> h_bits;
  float c  = fc[s * 64 + d * 2];
  float sn = fc[s * 64 + d * 2 + 1];
  size_t base = (size_t)s * row_stride + hh * 64 + d * 2;
  float x0 = bf2f(qk[base]), x1 = bf2f(qk[base + 1]);
  qk[base]     = f2bf((x0 * c - x1 * sn) * scale);
  qk[base + 1] = f2bf((x0 * sn + x1 * c) * scale);
}

// ---------------- V transpose: kv[s][512 + g*64+hd] -> vT[(g*64+hd)][s] ----------------
__global__ void transpose_v(const u16* __restrict__ kv, u16* __restrict__ vT) {
  int idx = blockIdx.x * blockDim.x + threadIdx.x;   // over KV*HD*S
  int s = idx & (S_LEN - 1);
  int t = idx >> 11;                                 // g*64+hd
  vT[idx] = kv[(size_t)s * 1024 + 512 + t];
}

// ---------------- Flash attention (causal, GQA), transposed scores ----------------
// block = (head h, 64 q rows); 4 waves x 16 q rows; BK=64 key tiles.
// S^T = K·Q^T  (C-layout: col=q per lane, row=key) -> softmax reduce mostly in-register.
// O^T = V^T·P^T accumulated in C-layout (col=q, row=hd). Output in-place over q.
__global__ __launch_bounds__(256) void attn_kernel(u16* __restrict__ q, const u16* __restrict__ k,
                                                   const u16* __restrict__ vT) {
  __shared__ __align__(16) u16 pS[4][16 * 72];   // per-wave P^T scratch: [q(16)][key(64)], stride 72
  const int h = blockIdx.x;
  const int qt = blockIdx.y;
  const int g = h >> 2;                          // kv head
  const int wave = threadIdx.x >> 6, lane = threadIdx.x & 63;
  const int quad = lane >> 4, l16 = lane & 15;
  const int qrow0 = qt * 64 + wave * 16;
  const int qglob = qrow0 + l16;                 // this lane's q column

  const size_t qoff = (size_t)qglob * DMODEL + h * HD_;
  bf16x8 qf0 = ld8(q + qoff + quad * 8);         // B-frag: n=q (lane), k=hd (pre-scaled by 1/8 in rope)
  bf16x8 qf1 = ld8(q + qoff + 32 + quad * 8);

  floatx4 Ofrag[4] = {};                         // O^T: row=hd(nt*16+quad*4+r), col=q(l16)
  float m_run = -INFINITY, l_run = 0.f;
  u16* myP = &pS[wave][0];

  for (int kt = 0; kt <= qt; kt++) {
    const int kbase = kt * 64;
    // ---- S^T = K·Q^T : 4 sub-tiles of 16 keys ----
    floatx4 sf[4];
#pragma unroll
    for (int sub = 0; sub < 4; sub++) {
      const u16* kb = k + (size_t)(kbase + sub * 16 + l16) * 1024 + g * HD_ + quad * 8;
      floatx4 s = {};
      s = mfma16(ld8(kb), qf0, s);           // A-frag: m=key, k=hd
      s = mfma16(ld8(kb + 32), qf1, s);
      sf[sub] = s;
    }
    if (kt == qt) {                          // diagonal tile: mask key > q
#pragma unroll
      for (int sub = 0; sub < 4; sub++)
#pragma unroll
        for (int r = 0; r < 4; r++)
          if (kbase + sub * 16 + quad * 4 + r > qglob) sf[sub][r] = -INFINITY;
    }
    // ---- per-q max: 16 regs in-lane, then cross-quad (2 shuffles) ----
    float mt = fmaxf(fmaxf(fmaxf(sf[0][0], sf[0][1]), fmaxf(sf[0][2], sf[0][3])),
                     fmaxf(fmaxf(sf[1][0], sf[1][1]), fmaxf(sf[1][2], sf[1][3])));
    mt = fmaxf(mt, fmaxf(fmaxf(fmaxf(sf[2][0], sf[2][1]), fmaxf(sf[2][2], sf[2][3])),
                         fmaxf(fmaxf(sf[3][0], sf[3][1]), fmaxf(sf[3][2], sf[3][3]))));
    mt = fmaxf(mt, __shfl_xor(mt, 16));
    mt = fmaxf(mt, __shfl_xor(mt, 32));
    const float m_new = fmaxf(m_run, mt);
    const float alpha = __expf(m_run - m_new);   // first tile: exp(-inf)=0
    // ---- exp + sum + pack P (bf16 pairs) ----
    float rs = 0.f;
    u32 pk[4][2];
#pragma unroll
    for (int sub = 0; sub < 4; sub++)
#pragma unroll
      for (int w = 0; w < 2; w++) {
        float p0 = __expf(sf[sub][2 * w]     - m_new);
        float p1 = __expf(sf[sub][2 * w + 1] - m_new);
        rs += p0 + p1;
        pk[sub][w] = (u32)f2bf(p0) | ((u32)f2bf(p1) << 16);
      }
    rs += __shfl_xor(rs, 16);
    rs += __shfl_xor(rs, 32);
    l_run = l_run * alpha + rs;
    m_run = m_new;
#pragma unroll
    for (int nt = 0; nt < 4; nt++) Ofrag[nt] *= alpha;
    // ---- V loads issued before the LDS fence (latency overlap) ----
    bf16x8 vf[4][2];
#pragma unroll
    for (int nt = 0; nt < 4; nt++) {
      const u16* vb = vT + ((size_t)g * HD_ + nt * 16 + l16) * S_LEN + kbase + quad * 8;
      vf[nt][0] = ld8(vb);
      vf[nt][1] = ld8(vb + 32);
    }
    // ---- P^T to LDS ([q][key], stride 72 u16) ----
#pragma unroll
    for (int sub = 0; sub < 4; sub++)
#pragma unroll
      for (int w = 0; w < 2; w++)
        *(u32*)&myP[l16 * 72 + sub * 16 + quad * 4 + 2 * w] = pk[sub][w];
    asm volatile("s_waitcnt lgkmcnt(0)" ::: "memory");  // wave-local LDS write->read fence
    bf16x8 pf0 = ld8(&myP[l16 * 72 + quad * 8]);        // B-frag: n=q, k=key(0..31)
    bf16x8 pf1 = ld8(&myP[l16 * 72 + 32 + quad * 8]);   //                 key(32..63)
    // ---- O^T += V^T · P^T ----
#pragma unroll
    for (int nt = 0; nt < 4; nt++) {
      Ofrag[nt] = mfma16(vf[nt][0], pf0, Ofrag[nt]);
      Ofrag[nt] = mfma16(vf[nt][1], pf1, Ofrag[nt]);
    }
  }

  const float inv = 1.0f / l_run;
#pragma unroll
  for (int nt = 0; nt < 4; nt++)
#pragma unroll
    for (int r = 0; r < 4; r++) {
      int hd = nt * 16 + quad * 4 + r;
      q[qoff + hd] = f2bf(Ofrag[nt][r] * inv);
    }
}

extern "C" void kernel_launch(void* const* d_in, const int* in_sizes, int n_in,
                              void* d_out, int out_size, void* d_ws, size_t ws_size,
                              hipStream_t stream) {
  const float* x  = (const float*)d_in[0];
  const float* fc = (const float*)d_in[1];
  const float* wq = (const float*)d_in[2];
  const float* wk = (const float*)d_in[3];
  const float* wv = (const float*)d_in[4];
  const float* wo = (const float*)d_in[5];
  float* out = (float*)d_out;

  // Workspace (28 MB, lifetime-reused):
  //   [0,8)MB   xb: x bf16        -> (after KV gemm) wo bf16
  //   [8,16)MB  R1: wq bf16       -> kv [8,12) + vT [12,14)
  //   [16,20)MB Wkv: wk||wv bf16 weights (1024 x 2048)
  //   [20,28)MB qb: q -> attn output (in-place)
  char* ws = (char*)d_ws;
  const size_t MB = 1024 * 1024;
  u16* xb  = (u16*)(ws);
  u16* R1  = (u16*)(ws + 8 * MB);
  u16* kv  = R1;                       // 2048 x 1024 (k cols 0-511, v cols 512-1023)
  u16* vTb = (u16*)(ws + 12 * MB);     // (KV*HD) x S
  u16* Wkv = (u16*)(ws + 16 * MB);
  u16* qb  = (u16*)(ws + 20 * MB);
  (void)ws_size; (void)n_in; (void)in_sizes; (void)out_size;

  // 1) x, wq -> bf16
  cvt_kernel<<<4096, 256, 0, stream>>>(x,  xb, 1048576);
  cvt_kernel<<<4096, 256, 0, stream>>>(wq, R1, 1048576);
  // 2) Q projection (R1=wq dies here)
  gemm_bt<1><<<dim3(16, 16), 256, 0, stream>>>(xb, R1, qb, S_LEN, DMODEL, DMODEL);
  // 3) wk||wv -> bf16, merged KV projection into kv (=R1 region)
  cvt_kernel<<<1024, 256, 0, stream>>>(wk, Wkv, 262144);
  cvt_kernel<<<1024, 256, 0, stream>>>(wv, Wkv + (size_t)512 * 2048, 262144);
  gemm_bt<1><<<dim3(8, 16), 256, 0, stream>>>(xb, Wkv, kv, S_LEN, 1024, DMODEL);
  // 4) xb (x) dead -> wo bf16
  cvt_kernel<<<4096, 256, 0, stream>>>(wo, xb, 1048576);
  // 5) RoPE: q pre-scaled by 1/sqrt(HD)=0.125 (exact in bf16); k unscaled
  rope_kernel<<<8192, 256, 0, stream>>>(qb, fc, 5, 2048, 0.125f);
  rope_kernel<<<2048, 256, 0, stream>>>(kv, fc, 3, 1024, 1.0f);
  // 6) V transpose
  transpose_v<<<4096, 256, 0, stream>>>(kv, vTb);
  // 7) causal GQA flash attention (output in-place into qb)
  attn_kernel<<<dim3(NH, S_LEN / 64), 256, 0, stream>>>(qb, kv, vTb);
  // 8) output projection (fp32 out)
  gemm_bt<0><<<dim3(16, 16), 256, 0, stream>>>(qb, xb, out, S_LEN, DMODEL, DMODEL);
}

// Round 5
// 318.035 us; speedup vs baseline: 1.4125x; 1.2837x over previous
//
#include <hip/hip_runtime.h>

typedef unsigned short u16;
typedef unsigned int u32;
typedef __bf16 bf16x8 __attribute__((ext_vector_type(8)));
typedef unsigned short ushort8 __attribute__((ext_vector_type(8)));
typedef float floatx4 __attribute__((ext_vector_type(4)));

#define S_LEN 2048
#define DMODEL 2048
#define NH 32
#define NKV 8
#define HD_ 64

__device__ __forceinline__ u16 f2bf(float f) {
  unsigned u = __builtin_bit_cast(unsigned, f);
  u += 0x7FFF + ((u >> 16) & 1);   // round-to-nearest-even
  return (u16)(u >> 16);
}
__device__ __forceinline__ float bf2f(u16 h) {
  unsigned u = ((unsigned)h) << 16;
  return __builtin_bit_cast(float, u);
}
__device__ __forceinline__ bf16x8 ld8(const u16* p) {
  return __builtin_bit_cast(bf16x8, *(const ushort8*)p);
}
__device__ __forceinline__ floatx4 mfma16(bf16x8 a, bf16x8 b, floatx4 c) {
  return __builtin_amdgcn_mfma_f32_16x16x32_bf16(a, b, c, 0, 0, 0);
}
__device__ __forceinline__ void gload_lds16(const u16* g, u16* l) {
  __builtin_amdgcn_global_load_lds((const __attribute__((address_space(1))) void*)g,
                                   (__attribute__((address_space(3))) void*)l, 16, 0, 0);
}

// ---------------- fp32 -> bf16 convert (vectorized) ----------------
__global__ void cvt_kernel(const float* __restrict__ in, u16* __restrict__ out, int n4) {
  int i = blockIdx.x * blockDim.x + threadIdx.x;
  if (i >= n4) return;
  float4 v = ((const float4*)in)[i];
  ((ushort4*)out)[i] = make_ushort4(f2bf(v.x), f2bf(v.y), f2bf(v.z), f2bf(v.w));
}

// ---------------- GEMM: C[M][N] = A[M][K] @ B[N][K]^T (bf16 in, fp32 acc) ----------------
// 128x128 tile, BK=32, 256 threads = 4 waves (2x2), each wave 64x64 = 4x4 MFMA tiles.
template <int OUT_BF16>
__global__ __launch_bounds__(256) void gemm_bt(const u16* __restrict__ A, const u16* __restrict__ B,
                                               void* __restrict__ C, int M, int N, int K) {
  __shared__ __align__(16) u16 As[128 * 32];
  __shared__ __align__(16) u16 Bs[128 * 32];
  const int tid = threadIdx.x;
  const int wave = tid >> 6, lane = tid & 63;
  const int quad = lane >> 4, l16 = lane & 15;
  const int bm = blockIdx.y * 128, bn = blockIdx.x * 128;
  const int wr = (wave >> 1) * 64, wc = (wave & 1) * 64;
  floatx4 acc[4][4] = {};

  for (int k0 = 0; k0 < K; k0 += 32) {
    for (int c = wave; c < 8; c += 4) {
      int e = c * 512 + lane * 8;          // element index in 128x32 tile
      int row = e >> 5, col = e & 31;
      gload_lds16(A + (size_t)(bm + row) * K + k0 + col, &As[c * 512]);
      gload_lds16(B + (size_t)(bn + row) * K + k0 + col, &Bs[c * 512]);
    }
    __syncthreads();
    bf16x8 af[4], bfr[4];
#pragma unroll
    for (int i = 0; i < 4; i++) {
      af[i]  = ld8(&As[(wr + i * 16 + l16) * 32 + quad * 8]);
      bfr[i] = ld8(&Bs[(wc + i * 16 + l16) * 32 + quad * 8]);
    }
#pragma unroll
    for (int mi = 0; mi < 4; mi++)
#pragma unroll
      for (int ni = 0; ni < 4; ni++)
        acc[mi][ni] = mfma16(af[mi], bfr[ni], acc[mi][ni]);
    __syncthreads();
  }

#pragma unroll
  for (int mi = 0; mi < 4; mi++)
#pragma unroll
    for (int ni = 0; ni < 4; ni++)
#pragma unroll
      for (int r = 0; r < 4; r++) {
        int row = bm + wr + mi * 16 + quad * 4 + r;
        int col = bn + wc + ni * 16 + l16;
        float v = acc[mi][ni][r];
        if (OUT_BF16) ((u16*)C)[(size_t)row * N + col] = f2bf(v);
        else          ((float*)C)[(size_t)row * N + col] = v;
      }
}

// ---------------- RoPE in-place on bf16, rows of `row_stride`, nheads = 1<<h_bits ----------------
__global__ void rope_kernel(u16* __restrict__ qk, const float* __restrict__ fc, int h_bits,
                            int row_stride, float scale) {
  int idx = blockIdx.x * blockDim.x + threadIdx.x;   // over S * nheads * 32 pairs
  int d = idx & 31;
  int t = idx >> 5;
  int hh = t & ((1 << h_bits) - 1);
  int s = t >> h_bits;
  float c  = fc[s * 64 + d * 2];
  float sn = fc[s * 64 + d * 2 + 1];
  size_t base = (size_t)s * row_stride + hh * 64 + d * 2;
  float x0 = bf2f(qk[base]), x1 = bf2f(qk[base + 1]);
  qk[base]     = f2bf((x0 * c - x1 * sn) * scale);
  qk[base + 1] = f2bf((x0 * sn + x1 * c) * scale);
}

// ---------------- V transpose: kv[s][512 + g*64+hd] -> vT[(g*64+hd)][s] ----------------
__global__ void transpose_v(const u16* __restrict__ kv, u16* __restrict__ vT) {
  int idx = blockIdx.x * blockDim.x + threadIdx.x;   // over KV*HD*S
  int s = idx & (S_LEN - 1);
  int t = idx >> 11;                                 // g*64+hd
  vT[idx] = kv[(size_t)s * 1024 + 512 + t];
}

// ---------------- Flash attention (causal, GQA), LDS-staged K/V, transposed scores ------------
// block = (head h, 64 q rows); 4 waves x 16 q rows; BK=64 key tiles.
// K/V tiles staged to LDS once per block (coalesced global -> reg -> ds_write, stride-72 pad);
// next tile's global loads issued right after the barrier (overlap compute).
// S^T = K·Q^T (C-layout: col=q, row=key); O^T = V^T·P^T. Output in-place over q.
__global__ __launch_bounds__(256) void attn_kernel(u16* __restrict__ q, const u16* __restrict__ k,
                                                   const u16* __restrict__ vT) {
  __shared__ __align__(16) u16 Ks[64 * 72];      // [key][hd], stride 72
  __shared__ __align__(16) u16 Vs[64 * 72];      // [hd][key], stride 72
  __shared__ __align__(16) u16 pS[4][16 * 72];   // per-wave P^T scratch [q][key], stride 72
  const int h = blockIdx.x;
  const int qt = (h & 1) ? (31 - (int)blockIdx.y) : (int)blockIdx.y;  // causal load-balance swizzle
  const int g = h >> 2;                          // kv head
  const int tid = threadIdx.x;
  const int wave = tid >> 6, lane = tid & 63;
  const int quad = lane >> 4, l16 = lane & 15;
  const int qglob = qt * 64 + wave * 16 + l16;   // this lane's q column

  const size_t qoff = (size_t)qglob * DMODEL + h * HD_;
  bf16x8 qf0 = ld8(q + qoff + quad * 8);         // B-frag: n=q, k=hd (pre-scaled 1/8 in rope)
  bf16x8 qf1 = ld8(q + qoff + 32 + quad * 8);

  // staging assignment: 512 chunks of 16B per tile; thread t owns chunks {t, t+256}
  const int r0 = tid >> 3,         o0 = (tid & 7) * 8;          // rows 0..31
  const int r1 = (tid + 256) >> 3, o1 = o0;                     // rows 32..63
  const u16* ksrc = k + g * HD_;                                // row stride 1024
  const u16* vsrc = vT + (size_t)g * HD_ * S_LEN;               // row stride 2048

  ushort8 kp0 = *(const ushort8*)(ksrc + (size_t)r0 * 1024 + o0);
  ushort8 kp1 = *(const ushort8*)(ksrc + (size_t)r1 * 1024 + o1);
  ushort8 vp0 = *(const ushort8*)(vsrc + (size_t)r0 * S_LEN + o0);
  ushort8 vp1 = *(const ushort8*)(vsrc + (size_t)r1 * S_LEN + o1);

  floatx4 Ofrag[4] = {};                         // O^T: row=hd(nt*16+quad*4+r), col=q(l16)
  float m_run = -INFINITY, l_run = 0.f;
  u16* myP = &pS[wave][0];

  for (int kt = 0; kt <= qt; kt++) {
    const int kbase = kt * 64;
    *(ushort8*)&Ks[r0 * 72 + o0] = kp0;
    *(ushort8*)&Ks[r1 * 72 + o1] = kp1;
    *(ushort8*)&Vs[r0 * 72 + o0] = vp0;
    *(ushort8*)&Vs[r1 * 72 + o1] = vp1;
    __syncthreads();
    if (kt < qt) {                               // prefetch next tile (overlaps compute below)
      const int nb = kbase + 64;
      kp0 = *(const ushort8*)(ksrc + (size_t)(nb + r0) * 1024 + o0);
      kp1 = *(const ushort8*)(ksrc + (size_t)(nb + r1) * 1024 + o1);
      vp0 = *(const ushort8*)(vsrc + (size_t)r0 * S_LEN + nb + o0);
      vp1 = *(const ushort8*)(vsrc + (size_t)r1 * S_LEN + nb + o1);
    }
    // ---- S^T = K·Q^T : 4 sub-tiles of 16 keys ----
    floatx4 sf[4];
#pragma unroll
    for (int sub = 0; sub < 4; sub++) {
      const u16* kb = &Ks[(sub * 16 + l16) * 72];
      floatx4 s = {};
      s = mfma16(ld8(kb + quad * 8), qf0, s);    // A-frag: m=key, k=hd
      s = mfma16(ld8(kb + 32 + quad * 8), qf1, s);
      sf[sub] = s;
    }
    if (kt == qt) {                              // diagonal tile: mask key > q
#pragma unroll
      for (int sub = 0; sub < 4; sub++)
#pragma unroll
        for (int r = 0; r < 4; r++)
          if (kbase + sub * 16 + quad * 4 + r > qglob) sf[sub][r] = -INFINITY;
    }
    // ---- per-q max: in-register + 2 shuffles ----
    float mt = fmaxf(fmaxf(fmaxf(sf[0][0], sf[0][1]), fmaxf(sf[0][2], sf[0][3])),
                     fmaxf(fmaxf(sf[1][0], sf[1][1]), fmaxf(sf[1][2], sf[1][3])));
    mt = fmaxf(mt, fmaxf(fmaxf(fmaxf(sf[2][0], sf[2][1]), fmaxf(sf[2][2], sf[2][3])),
                         fmaxf(fmaxf(sf[3][0], sf[3][1]), fmaxf(sf[3][2], sf[3][3]))));
    mt = fmaxf(mt, __shfl_xor(mt, 16));
    mt = fmaxf(mt, __shfl_xor(mt, 32));
    const float m_new = fmaxf(m_run, mt);
    const float alpha = __expf(m_run - m_new);   // first tile: exp(-inf)=0
    // ---- exp + sum + pack P (bf16 pairs) ----
    float rs = 0.f;
    u32 pk[4][2];
#pragma unroll
    for (int sub = 0; sub < 4; sub++)
#pragma unroll
      for (int w = 0; w < 2; w++) {
        float p0 = __expf(sf[sub][2 * w]     - m_new);
        float p1 = __expf(sf[sub][2 * w + 1] - m_new);
        rs += p0 + p1;
        pk[sub][w] = (u32)f2bf(p0) | ((u32)f2bf(p1) << 16);
      }
    rs += __shfl_xor(rs, 16);
    rs += __shfl_xor(rs, 32);
    l_run = l_run * alpha + rs;
    m_run = m_new;
#pragma unroll
    for (int nt = 0; nt < 4; nt++) Ofrag[nt] *= alpha;
    // ---- V frags from LDS ----
    bf16x8 vf[4][2];
#pragma unroll
    for (int nt = 0; nt < 4; nt++) {
      const u16* vb = &Vs[(nt * 16 + l16) * 72 + quad * 8];
      vf[nt][0] = ld8(vb);                       // keys 0..31 (chunk quad)
      vf[nt][1] = ld8(vb + 32);                  // keys 32..63
    }
    // ---- P^T to per-wave LDS scratch ----
#pragma unroll
    for (int sub = 0; sub < 4; sub++)
#pragma unroll
      for (int w = 0; w < 2; w++)
        *(u32*)&myP[l16 * 72 + sub * 16 + quad * 4 + 2 * w] = pk[sub][w];
    asm volatile("s_waitcnt lgkmcnt(0)" ::: "memory");  // wave-local LDS write->read fence
    bf16x8 pf0 = ld8(&myP[l16 * 72 + quad * 8]);
    bf16x8 pf1 = ld8(&myP[l16 * 72 + 32 + quad * 8]);
    // ---- O^T += V^T · P^T ----
#pragma unroll
    for (int nt = 0; nt < 4; nt++) {
      Ofrag[nt] = mfma16(vf[nt][0], pf0, Ofrag[nt]);
      Ofrag[nt] = mfma16(vf[nt][1], pf1, Ofrag[nt]);
    }
    __syncthreads();                             // protect Ks/Vs before next staging
  }

  const float inv = 1.0f / l_run;
#pragma unroll
  for (int nt = 0; nt < 4; nt++)
#pragma unroll
    for (int r = 0; r < 4; r++) {
      int hd = nt * 16 + quad * 4 + r;
      q[qoff + hd] = f2bf(Ofrag[nt][r] * inv);
    }
}

extern "C" void kernel_launch(void* const* d_in, const int* in_sizes, int n_in,
                              void* d_out, int out_size, void* d_ws, size_t ws_size,
                              hipStream_t stream) {
  const float* x  = (const float*)d_in[0];
  const float* fc = (const float*)d_in[1];
  const float* wq = (const float*)d_in[2];
  const float* wk = (const float*)d_in[3];
  const float* wv = (const float*)d_in[4];
  const float* wo = (const float*)d_in[5];
  float* out = (float*)d_out;

  // Workspace (28 MB, lifetime-reused):
  //   [0,8)MB   xb: x bf16        -> (after KV gemm) wo bf16
  //   [8,16)MB  R1: wq bf16       -> kv [8,12) + vT [12,14)
  //   [16,20)MB Wkv: wk||wv bf16 weights (1024 x 2048)
  //   [20,28)MB qb: q -> attn output (in-place)
  char* ws = (char*)d_ws;
  const size_t MB = 1024 * 1024;
  u16* xb  = (u16*)(ws);
  u16* R1  = (u16*)(ws + 8 * MB);
  u16* kv  = R1;                       // 2048 x 1024 (k cols 0-511, v cols 512-1023)
  u16* vTb = (u16*)(ws + 12 * MB);     // (KV*HD) x S
  u16* Wkv = (u16*)(ws + 16 * MB);
  u16* qb  = (u16*)(ws + 20 * MB);
  (void)ws_size; (void)n_in; (void)in_sizes; (void)out_size;

  // 1) x, wq -> bf16
  cvt_kernel<<<4096, 256, 0, stream>>>(x,  xb, 1048576);
  cvt_kernel<<<4096, 256, 0, stream>>>(wq, R1, 1048576);
  // 2) Q projection (R1=wq dies here)
  gemm_bt<1><<<dim3(16, 16), 256, 0, stream>>>(xb, R1, qb, S_LEN, DMODEL, DMODEL);
  // 3) wk||wv -> bf16, merged KV projection into kv (=R1 region)
  cvt_kernel<<<1024, 256, 0, stream>>>(wk, Wkv, 262144);
  cvt_kernel<<<1024, 256, 0, stream>>>(wv, Wkv + (size_t)512 * 2048, 262144);
  gemm_bt<1><<<dim3(8, 16), 256, 0, stream>>>(xb, Wkv, kv, S_LEN, 1024, DMODEL);
  // 4) xb (x) dead -> wo bf16
  cvt_kernel<<<4096, 256, 0, stream>>>(wo, xb, 1048576);
  // 5) RoPE: q pre-scaled by 1/sqrt(HD)=0.125 (exact in bf16); k unscaled
  rope_kernel<<<8192, 256, 0, stream>>>(qb, fc, 5, 2048, 0.125f);
  rope_kernel<<<2048, 256, 0, stream>>>(kv, fc, 3, 1024, 1.0f);
  // 6) V transpose
  transpose_v<<<4096, 256, 0, stream>>>(kv, vTb);
  // 7) causal GQA flash attention (output in-place into qb)
  attn_kernel<<<dim3(NH, S_LEN / 64), 256, 0, stream>>>(qb, kv, vTb);
  // 8) output projection (fp32 out)
  gemm_bt<0><<<dim3(16, 16), 256, 0, stream>>>(qb, xb, out, S_LEN, DMODEL, DMODEL);
}

// Round 6
// 308.455 us; speedup vs baseline: 1.4564x; 1.0311x over previous
//
#include <hip/hip_runtime.h>

typedef unsigned short u16;
typedef unsigned int u32;
typedef __bf16 bf16x8 __attribute__((ext_vector_type(8)));
typedef unsigned short ushort8 __attribute__((ext_vector_type(8)));
typedef float floatx4 __attribute__((ext_vector_type(4)));

#define S_LEN 2048
#define DMODEL 2048
#define NH 32
#define NKV 8
#define HD_ 64

__device__ __forceinline__ u16 f2bf(float f) {
  unsigned u = __builtin_bit_cast(unsigned, f);
  u += 0x7FFF + ((u >> 16) & 1);   // round-to-nearest-even
  return (u16)(u >> 16);
}
__device__ __forceinline__ float bf2f(u16 h) {
  unsigned u = ((unsigned)h) << 16;
  return __builtin_bit_cast(float, u);
}
__device__ __forceinline__ bf16x8 ld8(const u16* p) {
  return __builtin_bit_cast(bf16x8, *(const ushort8*)p);
}
__device__ __forceinline__ floatx4 mfma16(bf16x8 a, bf16x8 b, floatx4 c) {
  return __builtin_amdgcn_mfma_f32_16x16x32_bf16(a, b, c, 0, 0, 0);
}
__device__ __forceinline__ void gload_lds16(const u16* g, u16* l) {
  __builtin_amdgcn_global_load_lds((const __attribute__((address_space(1))) void*)g,
                                   (__attribute__((address_space(3))) void*)l, 16, 0, 0);
}

// ---------------- fp32 -> bf16 convert (vectorized) ----------------
__global__ void cvt_kernel(const float* __restrict__ in, u16* __restrict__ out, int n4) {
  int i = blockIdx.x * blockDim.x + threadIdx.x;
  if (i >= n4) return;
  float4 v = ((const float4*)in)[i];
  ((ushort4*)out)[i] = make_ushort4(f2bf(v.x), f2bf(v.y), f2bf(v.z), f2bf(v.w));
}

// ---------------- GEMM: C[M][N] = A[M][K] @ B[N][K]^T (bf16 in, fp32 acc) ----------------
// TM x TN tile, BK=32, 256 threads = 4 waves (2x2), wave does (TM/2)x(TN/2).
// lda = A row stride. Grid: (N/TN, M/TM).
template <int TM, int TN, int OUT_BF16>
__global__ __launch_bounds__(256) void gemm_bt(const u16* __restrict__ A, const u16* __restrict__ B,
                                               void* __restrict__ C, int M, int N, int K, int lda) {
  __shared__ __align__(16) u16 As[TM * 32];
  __shared__ __align__(16) u16 Bs[TN * 32];
  const int tid = threadIdx.x;
  const int wave = tid >> 6, lane = tid & 63;
  const int quad = lane >> 4, l16 = lane & 15;
  const int bm = blockIdx.y * TM, bn = blockIdx.x * TN;
  const int wr = (wave >> 1) * (TM / 2), wc = (wave & 1) * (TN / 2);
  constexpr int MI = TM / 32, NI = TN / 32;
  constexpr int NCH = (TM + TN) * 4;           // 16B chunks per K-step
  floatx4 acc[MI][NI] = {};

  for (int k0 = 0; k0 < K; k0 += 32) {
    // stage A,B tiles; wave handles 64 consecutive chunks (wave-uniform LDS base)
    for (int c0 = wave * 64; c0 < NCH; c0 += 256) {
      const int c = c0 + lane;
      if (c0 < TM * 4) {
        gload_lds16(A + (size_t)(bm + (c >> 2)) * lda + k0 + (c & 3) * 8, &As[c0 * 8]);
      } else {
        const int cc = c - TM * 4;
        gload_lds16(B + (size_t)(bn + (cc >> 2)) * K + k0 + (cc & 3) * 8, &Bs[(c0 - TM * 4) * 8]);
      }
    }
    __syncthreads();
    bf16x8 af[MI], bfr[NI];
#pragma unroll
    for (int i = 0; i < MI; i++) af[i]  = ld8(&As[(wr + i * 16 + l16) * 32 + quad * 8]);
#pragma unroll
    for (int i = 0; i < NI; i++) bfr[i] = ld8(&Bs[(wc + i * 16 + l16) * 32 + quad * 8]);
#pragma unroll
    for (int mi = 0; mi < MI; mi++)
#pragma unroll
      for (int ni = 0; ni < NI; ni++)
        acc[mi][ni] = mfma16(af[mi], bfr[ni], acc[mi][ni]);
    __syncthreads();
  }

#pragma unroll
  for (int mi = 0; mi < MI; mi++)
#pragma unroll
    for (int ni = 0; ni < NI; ni++)
#pragma unroll
      for (int r = 0; r < 4; r++) {
        int row = bm + wr + mi * 16 + quad * 4 + r;
        int col = bn + wc + ni * 16 + l16;
        float v = acc[mi][ni][r];
        if (OUT_BF16) ((u16*)C)[(size_t)row * N + col] = f2bf(v);
        else          ((float*)C)[(size_t)row * N + col] = v;
      }
}

// ---------------- RoPE in-place on bf16, rows of `row_stride`, nheads = 1<<h_bits ----------------
__global__ void rope_kernel(u16* __restrict__ qk, const float* __restrict__ fc, int h_bits,
                            int row_stride, float scale) {
  int idx = blockIdx.x * blockDim.x + threadIdx.x;   // over S * nheads * 32 pairs
  int d = idx & 31;
  int t = idx >> 5;
  int hh = t & ((1 << h_bits) - 1);
  int s = t >> h_bits;
  float c  = fc[s * 64 + d * 2];
  float sn = fc[s * 64 + d * 2 + 1];
  size_t base = (size_t)s * row_stride + hh * 64 + d * 2;
  float x0 = bf2f(qk[base]), x1 = bf2f(qk[base + 1]);
  qk[base]     = f2bf((x0 * c - x1 * sn) * scale);
  qk[base + 1] = f2bf((x0 * sn + x1 * c) * scale);
}

// ---------------- V transpose: kv[s][512 + g*64+hd] -> vT[(g*64+hd)][s] ----------------
__global__ void transpose_v(const u16* __restrict__ kv, u16* __restrict__ vT) {
  int idx = blockIdx.x * blockDim.x + threadIdx.x;   // over KV*HD*S
  int s = idx & (S_LEN - 1);
  int t = idx >> 11;                                 // g*64+hd
  vT[idx] = kv[(size_t)s * 1024 + 512 + t];
}

// ---------------- Flash attention (causal, GQA), LDS-staged K/V, no-max softmax ------------
// block = (head h, 64 q rows); 4 waves x 16 q rows; BK=64 key tiles.
// Scores bounded (|s|<~8 after 1/8 scale) -> skip running-max: P = exp2(s'), with
// log2e/8 folded into Q. l computed by MFMA ones-row trick (sum over keys on matrix pipe).
// S^T = K*Q^T (C-layout: col=q, row=key); O^T = V^T*P^T. Output in-place over q.
__global__ __launch_bounds__(256) void attn_kernel(u16* __restrict__ q, const u16* __restrict__ k,
                                                   const u16* __restrict__ vT) {
  __shared__ __align__(16) u16 Ks[64 * 72];      // [key][hd], stride 72
  __shared__ __align__(16) u16 Vs[64 * 72];      // [hd][key], stride 72
  __shared__ __align__(16) u16 pS[4][16 * 72];   // per-wave P^T scratch [q][key], stride 72
  const int h = blockIdx.x;
  const int qt = (h & 1) ? (31 - (int)blockIdx.y) : (int)blockIdx.y;  // causal load-balance swizzle
  const int g = h >> 2;                          // kv head
  const int tid = threadIdx.x;
  const int wave = tid >> 6, lane = tid & 63;
  const int quad = lane >> 4, l16 = lane & 15;
  const int qglob = qt * 64 + wave * 16 + l16;   // this lane's q column

  const size_t qoff = (size_t)qglob * DMODEL + h * HD_;
  bf16x8 qf0 = ld8(q + qoff + quad * 8);         // B-frag: n=q, k=hd (pre-scaled log2e/8 in rope)
  bf16x8 qf1 = ld8(q + qoff + 32 + quad * 8);

  const ushort8 ones_u = {0x3F80, 0x3F80, 0x3F80, 0x3F80, 0x3F80, 0x3F80, 0x3F80, 0x3F80};
  const bf16x8 onesA = __builtin_bit_cast(bf16x8, ones_u);

  // staging: 512 chunks of 16B per tile; thread t owns chunks {t, t+256}
  const int r0 = tid >> 3,         o0 = (tid & 7) * 8;          // rows 0..31
  const int r1 = (tid + 256) >> 3, o1 = o0;                     // rows 32..63
  const u16* ksrc = k + g * HD_;                                // row stride 1024
  const u16* vsrc = vT + (size_t)g * HD_ * S_LEN;               // row stride 2048

  ushort8 kp0 = *(const ushort8*)(ksrc + (size_t)r0 * 1024 + o0);
  ushort8 kp1 = *(const ushort8*)(ksrc + (size_t)r1 * 1024 + o1);
  ushort8 vp0 = *(const ushort8*)(vsrc + (size_t)r0 * S_LEN + o0);
  ushort8 vp1 = *(const ushort8*)(vsrc + (size_t)r1 * S_LEN + o1);

  floatx4 Ofrag[4] = {};                         // O^T: row=hd(nt*16+quad*4+r), col=q(l16)
  floatx4 lacc = {};                             // l (all 4 regs identical per lane)
  u16* myP = &pS[wave][0];

  for (int kt = 0; kt <= qt; kt++) {
    const int kbase = kt * 64;
    *(ushort8*)&Ks[r0 * 72 + o0] = kp0;
    *(ushort8*)&Ks[r1 * 72 + o1] = kp1;
    *(ushort8*)&Vs[r0 * 72 + o0] = vp0;
    *(ushort8*)&Vs[r1 * 72 + o1] = vp1;
    __syncthreads();
    if (kt < qt) {                               // prefetch next tile (overlaps compute below)
      const int nb = kbase + 64;
      kp0 = *(const ushort8*)(ksrc + (size_t)(nb + r0) * 1024 + o0);
      kp1 = *(const ushort8*)(ksrc + (size_t)(nb + r1) * 1024 + o1);
      vp0 = *(const ushort8*)(vsrc + (size_t)r0 * S_LEN + nb + o0);
      vp1 = *(const ushort8*)(vsrc + (size_t)r1 * S_LEN + nb + o1);
    }
    // ---- S^T = K*Q^T : 4 sub-tiles of 16 keys ----
    floatx4 sf[4];
#pragma unroll
    for (int sub = 0; sub < 4; sub++) {
      const u16* kb = &Ks[(sub * 16 + l16) * 72];
      floatx4 s = {};
      s = mfma16(ld8(kb + quad * 8), qf0, s);    // A-frag: m=key, k=hd
      s = mfma16(ld8(kb + 32 + quad * 8), qf1, s);
      sf[sub] = s;
    }
    if (kt == qt) {                              // diagonal tile: mask key > q
#pragma unroll
      for (int sub = 0; sub < 4; sub++)
#pragma unroll
        for (int r = 0; r < 4; r++)
          if (kbase + sub * 16 + quad * 4 + r > qglob) sf[sub][r] = -INFINITY;
    }
    // ---- P = exp2(s'), pack to bf16 pairs (round-nearest via +0x8000) ----
    u32 pk[4][2];
#pragma unroll
    for (int sub = 0; sub < 4; sub++)
#pragma unroll
      for (int w = 0; w < 2; w++) {
        float p0 = __builtin_amdgcn_exp2f(sf[sub][2 * w]);
        float p1 = __builtin_amdgcn_exp2f(sf[sub][2 * w + 1]);
        u32 b0 = __builtin_bit_cast(u32, p0) + 0x8000u;
        u32 b1 = __builtin_bit_cast(u32, p1) + 0x8000u;
        pk[sub][w] = __builtin_amdgcn_perm(b1, b0, 0x07060302);  // [bf(p0) | bf(p1)<<16]
      }
    // ---- V frags from LDS ----
    bf16x8 vf[4][2];
#pragma unroll
    for (int nt = 0; nt < 4; nt++) {
      const u16* vb = &Vs[(nt * 16 + l16) * 72 + quad * 8];
      vf[nt][0] = ld8(vb);
      vf[nt][1] = ld8(vb + 32);
    }
    // ---- P^T to per-wave LDS scratch ----
#pragma unroll
    for (int sub = 0; sub < 4; sub++)
#pragma unroll
      for (int w = 0; w < 2; w++)
        *(u32*)&myP[l16 * 72 + sub * 16 + quad * 4 + 2 * w] = pk[sub][w];
    asm volatile("s_waitcnt lgkmcnt(0)" ::: "memory");  // wave-local LDS write->read fence
    bf16x8 pf0 = ld8(&myP[l16 * 72 + quad * 8]);        // B-frag: n=q, k=key(0..31)
    bf16x8 pf1 = ld8(&myP[l16 * 72 + 32 + quad * 8]);   //                 key(32..63)
    // ---- O^T += V^T * P^T ; l += ones * P^T (matrix pipe) ----
#pragma unroll
    for (int nt = 0; nt < 4; nt++) {
      Ofrag[nt] = mfma16(vf[nt][0], pf0, Ofrag[nt]);
      Ofrag[nt] = mfma16(vf[nt][1], pf1, Ofrag[nt]);
    }
    lacc = mfma16(onesA, pf0, lacc);
    lacc = mfma16(onesA, pf1, lacc);
    __syncthreads();                             // protect Ks/Vs before next staging
  }

  const float inv = 1.0f / lacc[0];
#pragma unroll
  for (int nt = 0; nt < 4; nt++)
#pragma unroll
    for (int r = 0; r < 4; r++) {
      int hd = nt * 16 + quad * 4 + r;
      q[qoff + hd] = f2bf(Ofrag[nt][r] * inv);
    }
}

extern "C" void kernel_launch(void* const* d_in, const int* in_sizes, int n_in,
                              void* d_out, int out_size, void* d_ws, size_t ws_size,
                              hipStream_t stream) {
  const float* x  = (const float*)d_in[0];
  const float* fc = (const float*)d_in[1];
  const float* wq = (const float*)d_in[2];
  const float* wk = (const float*)d_in[3];
  const float* wv = (const float*)d_in[4];
  const float* wo = (const float*)d_in[5];
  float* out = (float*)d_out;

  // Workspace (24 MB, lifetime-reused):
  //   [0,8)MB   xb: x bf16            -> wo bf16 (after KV gemm)
  //   [8,16)MB  T:  wq bf16           -> wkv [8,12) -> vT [8,10) ; kv out [12,16)
  //   [16,24)MB qb: q -> attn output (in-place)
  char* ws = (char*)d_ws;
  const size_t MB = 1024 * 1024;
  u16* xb  = (u16*)(ws);
  u16* T   = (u16*)(ws + 8 * MB);
  u16* vTb = (u16*)(ws + 8 * MB);      // after wkv dead
  u16* kv  = (u16*)(ws + 12 * MB);     // 2048 x 1024 (k cols 0-511, v cols 512-1023)
  u16* qb  = (u16*)(ws + 16 * MB);
  (void)ws_size; (void)n_in; (void)in_sizes; (void)out_size;

  // 1) x, wq -> bf16
  cvt_kernel<<<4096, 256, 0, stream>>>(x,  xb, 1048576);
  cvt_kernel<<<4096, 256, 0, stream>>>(wq, T,  1048576);
  // 2) Q projection (128x64 tile -> 512 blocks); T=wq dies here
  gemm_bt<128, 64, 1><<<dim3(32, 16), 256, 0, stream>>>(xb, T, qb, S_LEN, DMODEL, DMODEL, DMODEL);
  // 3) wk||wv -> bf16 into T[0,4MB), merged KV projection (64x64 tile -> 512 blocks)
  cvt_kernel<<<1024, 256, 0, stream>>>(wk, T, 262144);
  cvt_kernel<<<1024, 256, 0, stream>>>(wv, T + (size_t)512 * 2048, 262144);
  gemm_bt<64, 64, 1><<<dim3(16, 32), 256, 0, stream>>>(xb, T, kv, S_LEN, 1024, DMODEL, DMODEL);
  // 4) xb (x) dead -> wo bf16
  cvt_kernel<<<4096, 256, 0, stream>>>(wo, xb, 1048576);
  // 5) RoPE: q pre-scaled by log2e/sqrt(HD); k unscaled
  rope_kernel<<<8192, 256, 0, stream>>>(qb, fc, 5, 2048, 0.18033688f);
  rope_kernel<<<2048, 256, 0, stream>>>(kv, fc, 3, 1024, 1.0f);
  // 6) V transpose (wkv dead -> vT at [8,10))
  transpose_v<<<4096, 256, 0, stream>>>(kv, vTb);
  // 7) causal GQA flash attention (output in-place into qb)
  attn_kernel<<<dim3(NH, S_LEN / 64), 256, 0, stream>>>(qb, kv, vTb);
  // 8) output projection (fp32 out, 128x64 tile -> 512 blocks)
  gemm_bt<128, 64, 0><<<dim3(32, 16), 256, 0, stream>>>(qb, xb, out, S_LEN, DMODEL, DMODEL, DMODEL);
}

// Round 8
// 245.630 us; speedup vs baseline: 1.8289x; 1.2558x over previous
//
#include <hip/hip_runtime.h>

typedef unsigned short u16;
typedef unsigned int u32;
typedef __bf16 bf16x8 __attribute__((ext_vector_type(8)));
typedef unsigned short ushort8 __attribute__((ext_vector_type(8)));
typedef float floatx4 __attribute__((ext_vector_type(4)));

#define S_LEN 2048
#define NH 32
#define NKV 8
#define HD_ 64
#define LDQ 3072   // qkv row stride: [q 0..2047 | k 2048..2559 | v 2560..3071]

__device__ __forceinline__ u16 f2bf(float f) {
  unsigned u = __builtin_bit_cast(unsigned, f);
  u += 0x7FFF + ((u >> 16) & 1);   // round-to-nearest-even
  return (u16)(u >> 16);
}
__device__ __forceinline__ float bf2f(u16 h) {
  unsigned u = ((unsigned)h) << 16;
  return __builtin_bit_cast(float, u);
}
__device__ __forceinline__ bf16x8 ld8(const u16* p) {
  return __builtin_bit_cast(bf16x8, *(const ushort8*)p);
}
__device__ __forceinline__ floatx4 mfma16(bf16x8 a, bf16x8 b, floatx4 c) {
  return __builtin_amdgcn_mfma_f32_16x16x32_bf16(a, b, c, 0, 0, 0);
}
// two fp32 -> packed bf16 pair (round-half-up via +0x8000, then byte-perm)
__device__ __forceinline__ u32 pk2bf(float a, float b) {
  u32 ua = __builtin_bit_cast(u32, a) + 0x8000u;
  u32 ub = __builtin_bit_cast(u32, b) + 0x8000u;
  return __builtin_amdgcn_perm(ub, ua, 0x07060302);   // [bf(a) | bf(b)<<16]
}
__device__ __forceinline__ ushort8 pack8(float4 a, float4 b) {
  union { u32 w[4]; ushort8 v; } u;
  u.w[0] = pk2bf(a.x, a.y); u.w[1] = pk2bf(a.z, a.w);
  u.w[2] = pk2bf(b.x, b.y); u.w[3] = pk2bf(b.z, b.w);
  return u.v;
}

// ---------------- Pipelined GEMM: C[M][N] = A[M][K] @ B[N][K]^T ----------------
// 128x64 tile, BK=64, 4 waves (2x2: 64x32 each). Register-prefetch staging:
// global loads for tile k+1 issue right after the barrier and are consumed
// (ds_write) one full iteration later -> full-iteration prefetch distance.
// fp32 inputs converted to bf16 during staging. LDS chunk-XOR swizzle keeps
// staging writes and fragment reads <=2 lanes/bank (free).
// B rows resolved across 3 segment arrays (fused wq|wk|wv); pass seg=BIG for single B.
template <int A_F32, int OUT_BF16>
__global__ __launch_bounds__(256) void gemm_pipe(
    const void* __restrict__ Avoid, const float* __restrict__ B0,
    const float* __restrict__ B1, const float* __restrict__ B2,
    int seg1, int seg2, void* __restrict__ C, int N, int K, int lda) {
  __shared__ __align__(16) u16 As[128 * 64];
  __shared__ __align__(16) u16 Bs[64 * 64];
  const int tid = threadIdx.x;
  const int wave = tid >> 6, lane = tid & 63;
  const int quad = lane >> 4, l16 = lane & 15;
  const int bm = blockIdx.y * 128, bn = blockIdx.x * 64;
  const int wr = (wave >> 1) * 64, wc = (wave & 1) * 32;
  const int crow = tid >> 3, col8 = tid & 7;     // staging: row base, 8-elem col chunk

  const float* Af = (const float*)Avoid;
  const u16*   Ab = (const u16*)Avoid;

  const float* bptr[2];
#pragma unroll
  for (int j = 0; j < 2; j++) {
    int r = bn + crow + j * 32;
    bptr[j] = (r < seg1) ? B0 + (size_t)r * K
            : (r < seg2) ? B1 + (size_t)(r - seg1) * K
                         : B2 + (size_t)(r - seg2) * K;
  }
  size_t aoff[4];
#pragma unroll
  for (int j = 0; j < 4; j++) aoff[j] = (size_t)(bm + crow + j * 32) * lda + col8 * 8;

  float4 a4[4][2]; ushort8 a8[4]; float4 b4[2][2];
  auto load_tiles = [&](int k0) {
    if constexpr (A_F32) {
#pragma unroll
      for (int j = 0; j < 4; j++) {
        a4[j][0] = *(const float4*)(Af + aoff[j] + k0);
        a4[j][1] = *(const float4*)(Af + aoff[j] + k0 + 4);
      }
    } else {
#pragma unroll
      for (int j = 0; j < 4; j++) a8[j] = *(const ushort8*)(Ab + aoff[j] + k0);
    }
#pragma unroll
    for (int j = 0; j < 2; j++) {
      b4[j][0] = *(const float4*)(bptr[j] + k0 + col8 * 8);
      b4[j][1] = *(const float4*)(bptr[j] + k0 + col8 * 8 + 4);
    }
  };

  floatx4 acc[4][2] = {};
  load_tiles(0);
  for (int k0 = 0; k0 < K; k0 += 64) {
#pragma unroll
    for (int j = 0; j < 4; j++) {
      const int row = crow + j * 32;
      ushort8 v;
      if constexpr (A_F32) v = pack8(a4[j][0], a4[j][1]);
      else                 v = a8[j];
      *(ushort8*)&As[row * 64 + ((col8 ^ (row & 7)) * 8)] = v;
    }
#pragma unroll
    for (int j = 0; j < 2; j++) {
      const int row = crow + j * 32;
      *(ushort8*)&Bs[row * 64 + ((col8 ^ (row & 7)) * 8)] = pack8(b4[j][0], b4[j][1]);
    }
    __syncthreads();
    if (k0 + 64 < K) load_tiles(k0 + 64);        // prefetch next tile (overlaps compute)
#pragma unroll
    for (int kh = 0; kh < 2; kh++) {
      bf16x8 af[4], bfr[2];
#pragma unroll
      for (int mi = 0; mi < 4; mi++) {
        const int row = wr + mi * 16 + l16;
        af[mi] = ld8(&As[row * 64 + (((kh * 4 + quad) ^ (row & 7)) * 8)]);
      }
#pragma unroll
      for (int ni = 0; ni < 2; ni++) {
        const int row = wc + ni * 16 + l16;
        bfr[ni] = ld8(&Bs[row * 64 + (((kh * 4 + quad) ^ (row & 7)) * 8)]);
      }
#pragma unroll
      for (int mi = 0; mi < 4; mi++)
#pragma unroll
        for (int ni = 0; ni < 2; ni++)
          acc[mi][ni] = mfma16(af[mi], bfr[ni], acc[mi][ni]);
    }
    __syncthreads();
  }

#pragma unroll
  for (int mi = 0; mi < 4; mi++)
#pragma unroll
    for (int ni = 0; ni < 2; ni++)
#pragma unroll
      for (int r = 0; r < 4; r++) {
        const int row = bm + wr + mi * 16 + quad * 4 + r;   // C/D: row=(lane>>4)*4+reg
        const int col = bn + wc + ni * 16 + l16;            //      col=lane&15
        if (OUT_BF16) ((u16*)C)[(size_t)row * N + col] = f2bf(acc[mi][ni][r]);
        else          ((float*)C)[(size_t)row * N + col] = acc[mi][ni][r];
      }
}

// ---------------- RoPE in-place on bf16, rows of `row_stride`, nheads = 1<<h_bits ----------------
__global__ void rope_kernel(u16* __restrict__ qk, const float* __restrict__ fc, int h_bits,
                            int row_stride, float scale) {
  int idx = blockIdx.x * blockDim.x + threadIdx.x;   // over S * nheads * 32 pairs
  int d = idx & 31;
  int t = idx >> 5;
  int hh = t & ((1 << h_bits) - 1);
  int s = t >> h_bits;
  float c  = fc[s * 64 + d * 2];
  float sn = fc[s * 64 + d * 2 + 1];
  size_t base = (size_t)s * row_stride + hh * 64 + d * 2;
  float x0 = bf2f(qk[base]), x1 = bf2f(qk[base + 1]);
  qk[base]     = f2bf((x0 * c - x1 * sn) * scale);
  qk[base + 1] = f2bf((x0 * sn + x1 * c) * scale);
}

// ---------------- V transpose: qkv[s][2560 + g*64+hd] -> vT[(g*64+hd)][s] ----------------
__global__ void transpose_v(const u16* __restrict__ qkv, u16* __restrict__ vT) {
  int idx = blockIdx.x * blockDim.x + threadIdx.x;   // over KV*HD*S
  int s = idx & (S_LEN - 1);
  int t = idx >> 11;                                 // g*64+hd
  vT[idx] = qkv[(size_t)s * LDQ + 2560 + t];
}

// ---------------- Flash attention (causal, GQA), LDS-staged K/V, no-max softmax ------------
// block = (head h, 64 q rows); 4 waves x 16 q rows; BK=64 key tiles.
// qkv is READ-ONLY here (q cols + k cols, stride LDQ); output goes to separate o buffer
// (row stride 2048). P = exp2(s'), log2e/8 folded into Q. l via MFMA ones-row.
__global__ __launch_bounds__(256) void attn_kernel(const u16* qkv, const u16* __restrict__ vT,
                                                   u16* __restrict__ o) {
  __shared__ __align__(16) u16 Ks[64 * 72];      // [key][hd], stride 72
  __shared__ __align__(16) u16 Vs[64 * 72];      // [hd][key], stride 72
  __shared__ __align__(16) u16 pS[4][16 * 72];   // per-wave P^T scratch [q][key], stride 72
  const int h = blockIdx.x;
  const int qt = (h & 1) ? (31 - (int)blockIdx.y) : (int)blockIdx.y;  // causal load-balance swizzle
  const int g = h >> 2;                          // kv head
  const int tid = threadIdx.x;
  const int wave = tid >> 6, lane = tid & 63;
  const int quad = lane >> 4, l16 = lane & 15;
  const int qglob = qt * 64 + wave * 16 + l16;   // this lane's q column

  const size_t qoff = (size_t)qglob * LDQ + h * HD_;
  bf16x8 qf0 = ld8(qkv + qoff + quad * 8);       // B-frag: n=q, k=hd (pre-scaled log2e/8)
  bf16x8 qf1 = ld8(qkv + qoff + 32 + quad * 8);

  const ushort8 ones_u = {0x3F80, 0x3F80, 0x3F80, 0x3F80, 0x3F80, 0x3F80, 0x3F80, 0x3F80};
  const bf16x8 onesA = __builtin_bit_cast(bf16x8, ones_u);

  // staging: 512 chunks of 16B per tile; thread t owns chunks {t, t+256}
  const int r0 = tid >> 3,         o0 = (tid & 7) * 8;          // rows 0..31
  const int r1 = (tid + 256) >> 3, o1 = o0;                     // rows 32..63
  const u16* ksrc = qkv + 2048 + g * HD_;                       // row stride LDQ
  const u16* vsrc = vT + (size_t)g * HD_ * S_LEN;               // row stride S_LEN

  ushort8 kp0 = *(const ushort8*)(ksrc + (size_t)r0 * LDQ + o0);
  ushort8 kp1 = *(const ushort8*)(ksrc + (size_t)r1 * LDQ + o1);
  ushort8 vp0 = *(const ushort8*)(vsrc + (size_t)r0 * S_LEN + o0);
  ushort8 vp1 = *(const ushort8*)(vsrc + (size_t)r1 * S_LEN + o1);

  floatx4 Ofrag[4] = {};                         // O^T: row=hd(nt*16+quad*4+r), col=q(l16)
  floatx4 lacc = {};                             // l (all 4 regs identical per lane)
  u16* myP = &pS[wave][0];

  for (int kt = 0; kt <= qt; kt++) {
    const int kbase = kt * 64;
    *(ushort8*)&Ks[r0 * 72 + o0] = kp0;
    *(ushort8*)&Ks[r1 * 72 + o1] = kp1;
    *(ushort8*)&Vs[r0 * 72 + o0] = vp0;
    *(ushort8*)&Vs[r1 * 72 + o1] = vp1;
    __syncthreads();
    if (kt < qt) {                               // prefetch next tile (overlaps compute below)
      const int nb = kbase + 64;
      kp0 = *(const ushort8*)(ksrc + (size_t)(nb + r0) * LDQ + o0);
      kp1 = *(const ushort8*)(ksrc + (size_t)(nb + r1) * LDQ + o1);
      vp0 = *(const ushort8*)(vsrc + (size_t)r0 * S_LEN + nb + o0);
      vp1 = *(const ushort8*)(vsrc + (size_t)r1 * S_LEN + nb + o1);
    }
    // ---- S^T = K*Q^T : 4 sub-tiles of 16 keys ----
    floatx4 sf[4];
#pragma unroll
    for (int sub = 0; sub < 4; sub++) {
      const u16* kb = &Ks[(sub * 16 + l16) * 72];
      floatx4 s = {};
      s = mfma16(ld8(kb + quad * 8), qf0, s);    // A-frag: m=key, k=hd
      s = mfma16(ld8(kb + 32 + quad * 8), qf1, s);
      sf[sub] = s;
    }
    if (kt == qt) {                              // diagonal tile: mask key > q
#pragma unroll
      for (int sub = 0; sub < 4; sub++)
#pragma unroll
        for (int r = 0; r < 4; r++)
          if (kbase + sub * 16 + quad * 4 + r > qglob) sf[sub][r] = -INFINITY;
    }
    // ---- P = exp2(s'), pack to bf16 pairs ----
    u32 pk[4][2];
#pragma unroll
    for (int sub = 0; sub < 4; sub++)
#pragma unroll
      for (int w = 0; w < 2; w++) {
        float p0 = __builtin_amdgcn_exp2f(sf[sub][2 * w]);
        float p1 = __builtin_amdgcn_exp2f(sf[sub][2 * w + 1]);
        pk[sub][w] = pk2bf(p0, p1);
      }
    // ---- V frags from LDS ----
    bf16x8 vf[4][2];
#pragma unroll
    for (int nt = 0; nt < 4; nt++) {
      const u16* vb = &Vs[(nt * 16 + l16) * 72 + quad * 8];
      vf[nt][0] = ld8(vb);
      vf[nt][1] = ld8(vb + 32);
    }
    // ---- P^T to per-wave LDS scratch ----
#pragma unroll
    for (int sub = 0; sub < 4; sub++)
#pragma unroll
      for (int w = 0; w < 2; w++)
        *(u32*)&myP[l16 * 72 + sub * 16 + quad * 4 + 2 * w] = pk[sub][w];
    asm volatile("s_waitcnt lgkmcnt(0)" ::: "memory");  // wave-local LDS write->read fence
    bf16x8 pf0 = ld8(&myP[l16 * 72 + quad * 8]);        // B-frag: n=q, k=key(0..31)
    bf16x8 pf1 = ld8(&myP[l16 * 72 + 32 + quad * 8]);   //                 key(32..63)
    // ---- O^T += V^T * P^T ; l += ones * P^T (matrix pipe) ----
#pragma unroll
    for (int nt = 0; nt < 4; nt++) {
      Ofrag[nt] = mfma16(vf[nt][0], pf0, Ofrag[nt]);
      Ofrag[nt] = mfma16(vf[nt][1], pf1, Ofrag[nt]);
    }
    lacc = mfma16(onesA, pf0, lacc);
    lacc = mfma16(onesA, pf1, lacc);
    __syncthreads();                             // protect Ks/Vs before next staging
  }

  const float inv = 1.0f / lacc[0];
  const size_t ooff = (size_t)qglob * 2048 + h * HD_;
#pragma unroll
  for (int nt = 0; nt < 4; nt++)
#pragma unroll
    for (int r = 0; r < 4; r++) {
      int hd = nt * 16 + quad * 4 + r;
      o[ooff + hd] = f2bf(Ofrag[nt][r] * inv);
    }
}

extern "C" void kernel_launch(void* const* d_in, const int* in_sizes, int n_in,
                              void* d_out, int out_size, void* d_ws, size_t ws_size,
                              hipStream_t stream) {
  const float* x  = (const float*)d_in[0];
  const float* fc = (const float*)d_in[1];
  const float* wq = (const float*)d_in[2];
  const float* wk = (const float*)d_in[3];
  const float* wv = (const float*)d_in[4];
  const float* wo = (const float*)d_in[5];
  float* out = (float*)d_out;

  // Workspace (22 MB):
  //   [0,12)MB  qkv bf16: 2048 x 3072 (q|k|v) — read-only after rope
  //   [12,14)MB vT bf16: (KV*HD) x S
  //   [14,22)MB ob bf16: 2048 x 2048 attention output
  char* ws = (char*)d_ws;
  const size_t MB = 1024 * 1024;
  u16* qkv = (u16*)(ws);
  u16* vTb = (u16*)(ws + 12 * MB);
  u16* ob  = (u16*)(ws + 14 * MB);
  (void)ws_size; (void)n_in; (void)in_sizes; (void)out_size;

  const int BIG = 1 << 30;
  // 1) fused QKV projection, fp32 in / bf16 out (conversion fused into staging)
  gemm_pipe<1, 1><<<dim3(48, 16), 256, 0, stream>>>(
      x, wq, wk, wv, 2048, 2560, qkv, LDQ, 2048, 2048);
  // 2) RoPE: q pre-scaled by log2e/sqrt(HD); k unscaled
  rope_kernel<<<8192, 256, 0, stream>>>(qkv, fc, 5, LDQ, 0.18033688f);
  rope_kernel<<<2048, 256, 0, stream>>>(qkv + 2048, fc, 3, LDQ, 1.0f);
  // 3) V transpose
  transpose_v<<<4096, 256, 0, stream>>>(qkv, vTb);
  // 4) causal GQA flash attention -> ob (qkv untouched)
  attn_kernel<<<dim3(NH, S_LEN / 64), 256, 0, stream>>>(qkv, vTb, ob);
  // 5) output projection, bf16 A / fp32 out
  gemm_pipe<0, 0><<<dim3(32, 16), 256, 0, stream>>>(
      ob, wo, wo, wo, BIG, BIG, out, 2048, 2048, 2048);
}

// Round 9
// 243.317 us; speedup vs baseline: 1.8463x; 1.0095x over previous
//
#include <hip/hip_runtime.h>

typedef unsigned short u16;
typedef unsigned int u32;
typedef __bf16 bf16x8 __attribute__((ext_vector_type(8)));
typedef unsigned short ushort8 __attribute__((ext_vector_type(8)));
typedef float floatx4 __attribute__((ext_vector_type(4)));

#define S_LEN 2048
#define NH 32
#define NKV 8
#define HD_ 64
#define LDQ 3072   // qkv row stride: [q 0..2047 | k 2048..2559 | v 2560..3071]

__device__ __forceinline__ u16 f2bf(float f) {
  unsigned u = __builtin_bit_cast(unsigned, f);
  u += 0x7FFF + ((u >> 16) & 1);   // round-to-nearest-even
  return (u16)(u >> 16);
}
__device__ __forceinline__ float bf2f(u16 h) {
  unsigned u = ((unsigned)h) << 16;
  return __builtin_bit_cast(float, u);
}
__device__ __forceinline__ bf16x8 ld8(const u16* p) {
  return __builtin_bit_cast(bf16x8, *(const ushort8*)p);
}
__device__ __forceinline__ floatx4 mfma16(bf16x8 a, bf16x8 b, floatx4 c) {
  return __builtin_amdgcn_mfma_f32_16x16x32_bf16(a, b, c, 0, 0, 0);
}
// two fp32 -> packed bf16 pair (round-half-up via +0x8000, then byte-perm)
__device__ __forceinline__ u32 pk2bf(float a, float b) {
  u32 ua = __builtin_bit_cast(u32, a) + 0x8000u;
  u32 ub = __builtin_bit_cast(u32, b) + 0x8000u;
  return __builtin_amdgcn_perm(ub, ua, 0x07060302);   // [bf(a) | bf(b)<<16]
}

// ---------------- fp32 -> bf16 convert (vectorized) ----------------
__global__ void cvt_kernel(const float* __restrict__ in, u16* __restrict__ out, int n4) {
  int i = blockIdx.x * blockDim.x + threadIdx.x;
  if (i >= n4) return;
  float4 v = ((const float4*)in)[i];
  ((ushort4*)out)[i] = make_ushort4(f2bf(v.x), f2bf(v.y), f2bf(v.z), f2bf(v.w));
}

// ---------------- Double-buffered GEMM: C[M][N] = A[M][K] @ B[N][K]^T (bf16 in) ------------
// TM x TN tile, BK=64, 4 waves (2x2). Single barrier per K-iter: while computing buf p,
// the next tile's global loads (issued at iter start) are ds_written into buf p^1; the
// vmcnt wait for them lands after the full compute phase. LDS chunk-XOR swizzle keeps
// all staging writes and fragment reads <=2 lanes/bank (conflict-free).
// Bytes staged per MFMA: 128x128 -> 0.25 KB (the m97 ratio); this is the L2-BW lever.
template <int TM, int TN, int OUT_BF16>
__global__ __launch_bounds__(256) void gemm_db(
    const u16* __restrict__ A, const u16* __restrict__ B, void* __restrict__ C,
    int ldc, int K, int lda) {
  __shared__ __align__(16) u16 As[2][TM * 64];
  __shared__ __align__(16) u16 Bs[2][TN * 64];
  const int tid = threadIdx.x;
  const int wave = tid >> 6, lane = tid & 63;
  const int quad = lane >> 4, l16 = lane & 15;
  const int bm = blockIdx.y * TM, bn = blockIdx.x * TN;
  const int wr = (wave >> 1) * (TM / 2), wc = (wave & 1) * (TN / 2);
  constexpr int MI = TM / 32, NI = TN / 32;
  const int crow = tid >> 3, col8 = tid & 7;     // staging: row base, 8-elem col chunk

  size_t aoff[MI], boff[NI];
#pragma unroll
  for (int j = 0; j < MI; j++) aoff[j] = (size_t)(bm + crow + j * 32) * lda + col8 * 8;
#pragma unroll
  for (int j = 0; j < NI; j++) boff[j] = (size_t)(bn + crow + j * 32) * K + col8 * 8;

  ushort8 a8[MI], b8[NI];
  auto load_tiles = [&](int k0) {
#pragma unroll
    for (int j = 0; j < MI; j++) a8[j] = *(const ushort8*)(A + aoff[j] + k0);
#pragma unroll
    for (int j = 0; j < NI; j++) b8[j] = *(const ushort8*)(B + boff[j] + k0);
  };
  auto write_tiles = [&](int p) {
#pragma unroll
    for (int j = 0; j < MI; j++) {
      const int row = crow + j * 32;
      *(ushort8*)&As[p][row * 64 + ((col8 ^ (row & 7)) * 8)] = a8[j];
    }
#pragma unroll
    for (int j = 0; j < NI; j++) {
      const int row = crow + j * 32;
      *(ushort8*)&Bs[p][row * 64 + ((col8 ^ (row & 7)) * 8)] = b8[j];
    }
  };

  floatx4 acc[MI][NI] = {};
  load_tiles(0);
  write_tiles(0);
  __syncthreads();
  int p = 0;
  for (int k0 = 0; k0 < K; k0 += 64) {
    const bool more = (k0 + 64 < K);
    if (more) load_tiles(k0 + 64);               // prefetch next tile (covered by compute)
#pragma unroll
    for (int kh = 0; kh < 2; kh++) {
      bf16x8 af[MI], bfr[NI];
#pragma unroll
      for (int mi = 0; mi < MI; mi++) {
        const int row = wr + mi * 16 + l16;
        af[mi] = ld8(&As[p][row * 64 + (((kh * 4 + quad) ^ (row & 7)) * 8)]);
      }
#pragma unroll
      for (int ni = 0; ni < NI; ni++) {
        const int row = wc + ni * 16 + l16;
        bfr[ni] = ld8(&Bs[p][row * 64 + (((kh * 4 + quad) ^ (row & 7)) * 8)]);
      }
#pragma unroll
      for (int mi = 0; mi < MI; mi++)
#pragma unroll
        for (int ni = 0; ni < NI; ni++)
          acc[mi][ni] = mfma16(af[mi], bfr[ni], acc[mi][ni]);
    }
    if (more) {
      write_tiles(p ^ 1);                        // vmcnt wait lands here, post-compute
      __syncthreads();                           // one barrier per iter
      p ^= 1;
    }
  }

#pragma unroll
  for (int mi = 0; mi < MI; mi++)
#pragma unroll
    for (int ni = 0; ni < NI; ni++)
#pragma unroll
      for (int r = 0; r < 4; r++) {
        const int row = bm + wr + mi * 16 + quad * 4 + r;   // C/D: row=(lane>>4)*4+reg
        const int col = bn + wc + ni * 16 + l16;            //      col=lane&15
        if (OUT_BF16) ((u16*)C)[(size_t)row * ldc + col] = f2bf(acc[mi][ni][r]);
        else          ((float*)C)[(size_t)row * ldc + col] = acc[mi][ni][r];
      }
}

// ---------------- RoPE in-place on bf16, rows of `row_stride`, nheads = 1<<h_bits ----------------
__global__ void rope_kernel(u16* __restrict__ qk, const float* __restrict__ fc, int h_bits,
                            int row_stride, float scale) {
  int idx = blockIdx.x * blockDim.x + threadIdx.x;   // over S * nheads * 32 pairs
  int d = idx & 31;
  int t = idx >> 5;
  int hh = t & ((1 << h_bits) - 1);
  int s = t >> h_bits;
  float c  = fc[s * 64 + d * 2];
  float sn = fc[s * 64 + d * 2 + 1];
  size_t base = (size_t)s * row_stride + hh * 64 + d * 2;
  float x0 = bf2f(qk[base]), x1 = bf2f(qk[base + 1]);
  qk[base]     = f2bf((x0 * c - x1 * sn) * scale);
  qk[base + 1] = f2bf((x0 * sn + x1 * c) * scale);
}

// ---------------- V transpose: qkv[s][2560 + g*64+hd] -> vT[(g*64+hd)][s] ----------------
__global__ void transpose_v(const u16* __restrict__ qkv, u16* __restrict__ vT) {
  int idx = blockIdx.x * blockDim.x + threadIdx.x;   // over KV*HD*S
  int s = idx & (S_LEN - 1);
  int t = idx >> 11;                                 // g*64+hd
  vT[idx] = qkv[(size_t)s * LDQ + 2560 + t];
}

// ---------------- Flash attention (causal, GQA), LDS-staged K/V, no-max softmax ------------
// block = (head h, 64 q rows); 4 waves x 16 q rows; BK=64 key tiles.
// qkv READ-ONLY (q + k cols, stride LDQ); output to separate o buffer (stride 2048).
// P = exp2(s'), log2e/8 folded into Q. l via MFMA ones-row.
__global__ __launch_bounds__(256) void attn_kernel(const u16* qkv, const u16* __restrict__ vT,
                                                   u16* __restrict__ o) {
  __shared__ __align__(16) u16 Ks[64 * 72];      // [key][hd], stride 72
  __shared__ __align__(16) u16 Vs[64 * 72];      // [hd][key], stride 72
  __shared__ __align__(16) u16 pS[4][16 * 72];   // per-wave P^T scratch [q][key], stride 72
  const int h = blockIdx.x;
  const int qt = (h & 1) ? (31 - (int)blockIdx.y) : (int)blockIdx.y;  // causal load-balance swizzle
  const int g = h >> 2;                          // kv head
  const int tid = threadIdx.x;
  const int wave = tid >> 6, lane = tid & 63;
  const int quad = lane >> 4, l16 = lane & 15;
  const int qglob = qt * 64 + wave * 16 + l16;   // this lane's q column

  const size_t qoff = (size_t)qglob * LDQ + h * HD_;
  bf16x8 qf0 = ld8(qkv + qoff + quad * 8);       // B-frag: n=q, k=hd (pre-scaled log2e/8)
  bf16x8 qf1 = ld8(qkv + qoff + 32 + quad * 8);

  const ushort8 ones_u = {0x3F80, 0x3F80, 0x3F80, 0x3F80, 0x3F80, 0x3F80, 0x3F80, 0x3F80};
  const bf16x8 onesA = __builtin_bit_cast(bf16x8, ones_u);

  // staging: 512 chunks of 16B per tile; thread t owns chunks {t, t+256}
  const int r0 = tid >> 3,         o0 = (tid & 7) * 8;          // rows 0..31
  const int r1 = (tid + 256) >> 3, o1 = o0;                     // rows 32..63
  const u16* ksrc = qkv + 2048 + g * HD_;                       // row stride LDQ
  const u16* vsrc = vT + (size_t)g * HD_ * S_LEN;               // row stride S_LEN

  ushort8 kp0 = *(const ushort8*)(ksrc + (size_t)r0 * LDQ + o0);
  ushort8 kp1 = *(const ushort8*)(ksrc + (size_t)r1 * LDQ + o1);
  ushort8 vp0 = *(const ushort8*)(vsrc + (size_t)r0 * S_LEN + o0);
  ushort8 vp1 = *(const ushort8*)(vsrc + (size_t)r1 * S_LEN + o1);

  floatx4 Ofrag[4] = {};                         // O^T: row=hd(nt*16+quad*4+r), col=q(l16)
  floatx4 lacc = {};                             // l (all 4 regs identical per lane)
  u16* myP = &pS[wave][0];

  for (int kt = 0; kt <= qt; kt++) {
    const int kbase = kt * 64;
    *(ushort8*)&Ks[r0 * 72 + o0] = kp0;
    *(ushort8*)&Ks[r1 * 72 + o1] = kp1;
    *(ushort8*)&Vs[r0 * 72 + o0] = vp0;
    *(ushort8*)&Vs[r1 * 72 + o1] = vp1;
    __syncthreads();
    if (kt < qt) {                               // prefetch next tile (overlaps compute below)
      const int nb = kbase + 64;
      kp0 = *(const ushort8*)(ksrc + (size_t)(nb + r0) * LDQ + o0);
      kp1 = *(const ushort8*)(ksrc + (size_t)(nb + r1) * LDQ + o1);
      vp0 = *(const ushort8*)(vsrc + (size_t)r0 * S_LEN + nb + o0);
      vp1 = *(const ushort8*)(vsrc + (size_t)r1 * S_LEN + nb + o1);
    }
    // ---- S^T = K*Q^T : 4 sub-tiles of 16 keys ----
    floatx4 sf[4];
#pragma unroll
    for (int sub = 0; sub < 4; sub++) {
      const u16* kb = &Ks[(sub * 16 + l16) * 72];
      floatx4 s = {};
      s = mfma16(ld8(kb + quad * 8), qf0, s);    // A-frag: m=key, k=hd
      s = mfma16(ld8(kb + 32 + quad * 8), qf1, s);
      sf[sub] = s;
    }
    if (kt == qt) {                              // diagonal tile: mask key > q
#pragma unroll
      for (int sub = 0; sub < 4; sub++)
#pragma unroll
        for (int r = 0; r < 4; r++)
          if (kbase + sub * 16 + quad * 4 + r > qglob) sf[sub][r] = -INFINITY;
    }
    // ---- P = exp2(s'), pack to bf16 pairs ----
    u32 pk[4][2];
#pragma unroll
    for (int sub = 0; sub < 4; sub++)
#pragma unroll
      for (int w = 0; w < 2; w++) {
        float p0 = __builtin_amdgcn_exp2f(sf[sub][2 * w]);
        float p1 = __builtin_amdgcn_exp2f(sf[sub][2 * w + 1]);
        pk[sub][w] = pk2bf(p0, p1);
      }
    // ---- V frags from LDS ----
    bf16x8 vf[4][2];
#pragma unroll
    for (int nt = 0; nt < 4; nt++) {
      const u16* vb = &Vs[(nt * 16 + l16) * 72 + quad * 8];
      vf[nt][0] = ld8(vb);
      vf[nt][1] = ld8(vb + 32);
    }
    // ---- P^T to per-wave LDS scratch ----
#pragma unroll
    for (int sub = 0; sub < 4; sub++)
#pragma unroll
      for (int w = 0; w < 2; w++)
        *(u32*)&myP[l16 * 72 + sub * 16 + quad * 4 + 2 * w] = pk[sub][w];
    asm volatile("s_waitcnt lgkmcnt(0)" ::: "memory");  // wave-local LDS write->read fence
    bf16x8 pf0 = ld8(&myP[l16 * 72 + quad * 8]);        // B-frag: n=q, k=key(0..31)
    bf16x8 pf1 = ld8(&myP[l16 * 72 + 32 + quad * 8]);   //                 key(32..63)
    // ---- O^T += V^T * P^T ; l += ones * P^T (matrix pipe) ----
#pragma unroll
    for (int nt = 0; nt < 4; nt++) {
      Ofrag[nt] = mfma16(vf[nt][0], pf0, Ofrag[nt]);
      Ofrag[nt] = mfma16(vf[nt][1], pf1, Ofrag[nt]);
    }
    lacc = mfma16(onesA, pf0, lacc);
    lacc = mfma16(onesA, pf1, lacc);
    __syncthreads();                             // protect Ks/Vs before next staging
  }

  const float inv = 1.0f / lacc[0];
  const size_t ooff = (size_t)qglob * 2048 + h * HD_;
#pragma unroll
  for (int nt = 0; nt < 4; nt++)
#pragma unroll
    for (int r = 0; r < 4; r++) {
      int hd = nt * 16 + quad * 4 + r;
      o[ooff + hd] = f2bf(Ofrag[nt][r] * inv);
    }
}

extern "C" void kernel_launch(void* const* d_in, const int* in_sizes, int n_in,
                              void* d_out, int out_size, void* d_ws, size_t ws_size,
                              hipStream_t stream) {
  const float* x  = (const float*)d_in[0];
  const float* fc = (const float*)d_in[1];
  const float* wq = (const float*)d_in[2];
  const float* wk = (const float*)d_in[3];
  const float* wv = (const float*)d_in[4];
  const float* wo = (const float*)d_in[5];
  float* out = (float*)d_out;

  // Workspace (30 MB — r3-proven size). Lifetimes:
  //   [0,12)MB  qkv bf16: 2048 x 3072 (q|k|v), written by QKV gemm, read-only after rope
  //   [12,24)MB wb bf16: wq|wk|wv (3072 x 2048) — dead after QKV gemm
  //   [12,14)MB vT bf16 (after wb dead)
  //   [14,22)MB wob bf16 (cvt'd after QKV gemm)
  //   [22,30)MB ob bf16: attention output
  // x bf16 (8 MB) lives in d_out (16.8 MB) — overwritten by the final O-GEMM.
  char* ws = (char*)d_ws;
  const size_t MB = 1024 * 1024;
  u16* qkv = (u16*)(ws);
  u16* wb  = (u16*)(ws + 12 * MB);
  u16* vTb = (u16*)(ws + 12 * MB);
  u16* wob = (u16*)(ws + 14 * MB);
  u16* ob  = (u16*)(ws + 22 * MB);
  u16* xb  = (u16*)d_out;
  (void)ws_size; (void)n_in; (void)in_sizes; (void)out_size;

  // 1) x, wq|wk|wv -> bf16
  cvt_kernel<<<4096, 256, 0, stream>>>(x,  xb, 1048576);
  cvt_kernel<<<4096, 256, 0, stream>>>(wq, wb, 1048576);
  cvt_kernel<<<1024, 256, 0, stream>>>(wk, wb + (size_t)2048 * 2048, 262144);
  cvt_kernel<<<1024, 256, 0, stream>>>(wv, wb + (size_t)2560 * 2048, 262144);
  // 2) fused QKV projection (128x128, all-bf16, dbuf)
  gemm_db<128, 128, 1><<<dim3(24, 16), 256, 0, stream>>>(xb, wb, qkv, LDQ, 2048, 2048);
  // 3) wo -> bf16 (wb region dead now)
  cvt_kernel<<<4096, 256, 0, stream>>>(wo, wob, 1048576);
  // 4) RoPE: q pre-scaled by log2e/sqrt(HD); k unscaled
  rope_kernel<<<8192, 256, 0, stream>>>(qkv, fc, 5, LDQ, 0.18033688f);
  rope_kernel<<<2048, 256, 0, stream>>>(qkv + 2048, fc, 3, LDQ, 1.0f);
  // 5) V transpose
  transpose_v<<<4096, 256, 0, stream>>>(qkv, vTb);
  // 6) causal GQA flash attention -> ob
  attn_kernel<<<dim3(NH, S_LEN / 64), 256, 0, stream>>>(qkv, vTb, ob);
  // 7) output projection (128x64, all-bf16, dbuf, fp32 out) — overwrites xb scratch
  gemm_db<128, 64, 0><<<dim3(32, 16), 256, 0, stream>>>(ob, wob, out, 2048, 2048, 2048);
}